// Round 6
// baseline (692.209 us; speedup 1.0000x reference)
//
#include <hip/hip_runtime.h>

#define K_CODES 4096
#define D 256
#define N_VEC 32768
#define N_ELEM 8388608   // 32*256*32*32
#define WINDOW 3.5e-4f
#define W_APPEND 4.0e-4f // candidate-append window (> WINDOW: covers <= edge)
#define CMAX 128         // candidate slots per position; overflow -> full scan
#define RG 8             // rescan positions per group
#define RSLICE 256       // rescan codes per slice

typedef _Float16 f16x8 __attribute__((ext_vector_type(8)));
typedef float f32x4 __attribute__((ext_vector_type(4)));

// ws layout (bytes)
#define WS_LOSS 0
#define WS_COUNT 8
#define WS_DONE 16
#define WS_COUNT2 24
#define WS_IDX 256
#define WS_LIST (WS_IDX + N_VEC * 4)
#define WS_ESQ (WS_LIST + N_VEC * 4)
#define WS_ZSQ (WS_ESQ + K_CODES * 4)
#define WS_APACK (WS_ZSQ + N_VEC * 4)                    // f16 frag-order z
#define WS_BPACK (WS_APACK + (size_t)N_VEC * 256 * 2)    // f16 frag-order cb
// Bp padded +64KB: pipelined reload reads one step (32KB) past the end
#define WS_RFIN (WS_BPACK + (size_t)K_CODES * 256 * 2 + 65536)
#define WS_ZT (WS_RFIN + (size_t)N_VEC * 8)              // f32 z^T [N_VEC][D]
#define WS_NEED_ZT (WS_ZT + (size_t)N_VEC * D * 4)
#define WS_CNT WS_NEED_ZT                                // u32[N_VEC]
#define WS_CANDL (WS_CNT + (size_t)N_VEC * 4)            // u16[N_VEC][CMAX]
#define WS_LISTB (WS_CANDL + (size_t)N_VEC * CMAX * 2)   // int[N_VEC]
#define WS_NEED_CAND (WS_LISTB + (size_t)N_VEC * 4)

// prep fusion block regions
#define PREP_PZ 4096    // pack_z2: 1M frag-slots / 256
#define PREP_PCB 512    // pack_cb2: 128K frag-slots / 256
#define PREP_ESQ 1024
#define PREP_ZSQ 128
#define PREP_BLOCKS (PREP_PZ + PREP_PCB + PREP_ESQ + PREP_ZSQ)

__device__ __forceinline__ unsigned long long pack_key(float s, int idx) {
  const unsigned u = __float_as_uint(s);
  const unsigned mk = (u & 0x80000000u) ? ~u : (u | 0x80000000u);
  return ((unsigned long long)mk << 12) | (unsigned long long)(unsigned)idx;
}
__device__ __forceinline__ float key_score(unsigned long long k) {
  const unsigned mk = (unsigned)(k >> 12);
  const unsigned u = (mk & 0x80000000u) ? (mk & 0x7fffffffu) : ~mk;
  return __uint_as_float(u);
}

// opaque identity: result can't be rematerialized -> forces register residency
__device__ __forceinline__ void pin_frag(f16x8& v) {
  asm volatile("" : "+v"(v));
}

// ---- e_sq body: fp32-squared terms, f64 accumulate, f32 round (frozen) -----
__device__ void esq_body(int bx, const float* __restrict__ cb,
                         float* __restrict__ esq) {
  const int lane = threadIdx.x & 63;
  const int k = bx * 4 + (threadIdx.x >> 6);
  const float* row = cb + (size_t)k * D;
  double s = 0.;
#pragma unroll
  for (int j = 0; j < 4; ++j) {
    const float v = row[lane + 64 * j];
    s += (double)__fmul_rn(v, v);
  }
#pragma unroll
  for (int off = 32; off > 0; off >>= 1) s += __shfl_down(s, off, 64);
  if (lane == 0) esq[k] = (float)s;
}

// ---- z_sq body (frozen: deterministic per-position order) ------------------
__device__ void zsq_body(int bx, const float* __restrict__ z,
                         float* __restrict__ zsq) {
  const int n = bx * 256 + threadIdx.x;
  const int b = n >> 10;
  const int hw = n & 1023;
  const float* p = z + ((size_t)b << 18) + hw;
  double a0 = 0., a1 = 0., a2 = 0., a3 = 0.;
  for (int c = 0; c < D; c += 4) {
    const float v0 = p[(size_t)(c + 0) << 10];
    const float v1 = p[(size_t)(c + 1) << 10];
    const float v2 = p[(size_t)(c + 2) << 10];
    const float v3 = p[(size_t)(c + 3) << 10];
    a0 += (double)__fmul_rn(v0, v0);
    a1 += (double)__fmul_rn(v1, v1);
    a2 += (double)__fmul_rn(v2, v2);
    a3 += (double)__fmul_rn(v3, v3);
  }
  zsq[n] = (float)((a0 + a1) + (a2 + a3));
}

// ---- pack z -> MFMA-fragment order (+ f32 transpose zT) --------------------
__device__ void pack_z2_body(int bx, const float* __restrict__ z,
                             _Float16* __restrict__ Ap,
                             float* __restrict__ zT) {
  const int t = bx * 256 + threadIdx.x;   // [0, 1048576)
  const int lane = t & 63;
  const int fid = t >> 6;                 // [0, 16384)
  const int ks = fid & 7;
  const int grp = fid >> 3;               // 16-row group
  const int n = grp * 16 + (lane & 15);
  const int d = ks * 32 + ((lane >> 4) << 3);
  const int b = n >> 10, hw = n & 1023;
  const float* p = z + ((size_t)b << 18) + ((size_t)d << 10) + hw;
  float v[8];
  f16x8 H;
#pragma unroll
  for (int j = 0; j < 8; ++j) {
    v[j] = p[(size_t)j << 10];
    H[j] = (_Float16)v[j];
  }
  *(f16x8*)(Ap + (size_t)t * 8) = H;
  if (zT) {  // same float values, transposed layout -> coalesced rescan reads
    float4* o = (float4*)(zT + (size_t)n * D + d);
    o[0] = make_float4(v[0], v[1], v[2], v[3]);
    o[1] = make_float4(v[4], v[5], v[6], v[7]);
  }
}

// ---- pack cb -> MFMA-fragment order, f16(256*e) ----------------------------
__device__ void pack_cb2_body(int bx, const float* __restrict__ cb,
                              _Float16* __restrict__ Bp) {
  const int t = bx * 256 + threadIdx.x;   // [0, 131072)
  const int lane = t & 63;
  const int fid = t >> 6;                 // [0, 2048)
  const int ks = fid & 7;
  const int grp = fid >> 3;               // [0, 256)
  const int k = grp * 16 + (lane & 15);
  const int d = ks * 32 + ((lane >> 4) << 3);
  const float* p = cb + (size_t)k * D + d;
  f16x8 H;
#pragma unroll
  for (int j = 0; j < 8; ++j) H[j] = (_Float16)(p[j] * 256.f);
  *(f16x8*)(Bp + (size_t)t * 8) = H;
}

// ---- fused prep ------------------------------------------------------------
__global__ __launch_bounds__(256) void prep_kernel(
    const float* __restrict__ z, const float* __restrict__ cb,
    float* __restrict__ esq, float* __restrict__ zsq,
    _Float16* __restrict__ Ap, _Float16* __restrict__ Bp,
    float* __restrict__ zT) {
  const int b = blockIdx.x;
  if (b < PREP_PZ) {
    pack_z2_body(b, z, Ap, zT);
  } else if (b < PREP_PZ + PREP_PCB) {
    pack_cb2_body(b - PREP_PZ, cb, Bp);
  } else if (b < PREP_PZ + PREP_PCB + PREP_ESQ) {
    esq_body(b - PREP_PZ - PREP_PCB, cb, esq);
  } else {
    zsq_body(b - PREP_PZ - PREP_PCB - PREP_ESQ, z, zsq);
  }
}

// ---- barrier-free MFMA distance + top-2 + CANDIDATE COLLECTION -------------
// R3-proven geometry: 256 blocks x 128 n-rows, 8 waves (wn 0..1 x wc 0..3),
// A pinned in VGPRs (a[4][8]), B single 8-frag buffer with in-cluster reload,
// acc double-buffered (fold hides under next cluster).
// NEW: every score s < min(thr,s1)+W_APPEND appends its code to cand[n]
// (thr = cross-quad running min, shuffled once per fold). SOUNDNESS: the
// design already requires WINDOW >= 2*coarse_err (non-flagged positions
// trust coarse m1). Hence any code that can win or tie exactly has
// coarse(k) <= m1 + 2err < running_min + W_APPEND -> always appended.
// Excluded codes are strictly worse than the exact winner -> candidate-set
// min == full-scan min, bit-identical. Overflow (cnt>CMAX) -> listB full scan.
#define CLUSTER(ACC, SN)                                                     \
  {                                                                          \
    __builtin_amdgcn_s_setprio(1);                                           \
    _Pragma("unroll") for (int ks = 0; ks < 8; ++ks) {                       \
      ACC[0] = __builtin_amdgcn_mfma_f32_16x16x32_f16(                       \
          b[ks], a[0][ks], ks ? ACC[0] : z4, 0, 0, 0);                       \
      ACC[1] = __builtin_amdgcn_mfma_f32_16x16x32_f16(                       \
          b[ks], a[1][ks], ks ? ACC[1] : z4, 0, 0, 0);                       \
      ACC[2] = __builtin_amdgcn_mfma_f32_16x16x32_f16(                       \
          b[ks], a[2][ks], ks ? ACC[2] : z4, 0, 0, 0);                       \
      ACC[3] = __builtin_amdgcn_mfma_f32_16x16x32_f16(                       \
          b[ks], a[3][ks], ks ? ACC[3] : z4, 0, 0, 0);                       \
      b[ks] = *(const f16x8*)(bbase + (size_t)(SN)*16384 + ks * 512);        \
    }                                                                        \
    __builtin_amdgcn_s_setprio(0);                                           \
  }

#define FOLD(ACC, S, EV)                                                     \
  {                                                                          \
    const int cb0 = (S)*64 + crow;                                           \
    const float ev[4] = {(EV).x, (EV).y, (EV).z, (EV).w};                    \
    _Pragma("unroll") for (int r = 0; r < 4; ++r) {                          \
      const int code = cb0 + r;                                              \
      _Pragma("unroll") for (int ni = 0; ni < 4; ++ni) {                     \
        const float s = fmaf(ACC[ni][r], -0.0078125f, ev[r]);                \
        if (candl) {                                                         \
          if (s < fminf(thr[ni], s1[ni]) + W_APPEND) {                       \
            const unsigned pp = atomicAdd(&cnt[npos[ni]], 1u);               \
            if (pp < CMAX)                                                   \
              candl[(size_t)npos[ni] * CMAX + pp] = (unsigned short)code;    \
          }                                                                  \
        }                                                                    \
        s2[ni] = fminf(fmaxf(s, s1[ni]), s2[ni]);                            \
        if (s < s1[ni]) i1[ni] = code;                                       \
        s1[ni] = fminf(s1[ni], s);                                           \
      }                                                                      \
    }                                                                        \
    if (candl) {                                                             \
      _Pragma("unroll") for (int ni = 0; ni < 4; ++ni) {                     \
        const float m_ = fminf(s1[ni], __shfl_xor(s1[ni], 16, 64));          \
        thr[ni] = fminf(m_, __shfl_xor(m_, 32, 64));                         \
      }                                                                      \
    }                                                                        \
  }

__global__ __launch_bounds__(512, 2) void dist2_kernel(
    const _Float16* __restrict__ Ap, const _Float16* __restrict__ Bp,
    const float* __restrict__ esq, int* __restrict__ idx,
    int* __restrict__ list, unsigned int* __restrict__ count,
    unsigned long long* __restrict__ rfin, unsigned int* __restrict__ cnt,
    unsigned short* __restrict__ candl, int* __restrict__ listB,
    unsigned int* __restrict__ count2) {
  __shared__ unsigned long long mb[128][4][2];  // 8 KB epilogue merge buffer
  const int tid = threadIdx.x;
  const int lane = tid & 63;
  const int w = tid >> 6;
  const int wn = w >> 2;   // n-group  (0..1)
  const int wc = w & 3;    // code-col (0..3)
  const int n0 = blockIdx.x * 128;

  // A frags: this wave's 64 n-rows x full K=256 -> 32 x f16x8 = 128 VGPRs
  f16x8 a[4][8];
  {
    const _Float16* ab =
        Ap + (size_t)((n0 + wn * 64) >> 4) * 4096 + (size_t)lane * 8;
#pragma unroll
    for (int ni = 0; ni < 4; ++ni)
#pragma unroll
      for (int ks = 0; ks < 8; ++ks) {
        a[ni][ks] = *(const f16x8*)(ab + (size_t)(ni * 8 + ks) * 512);
        pin_frag(a[ni][ks]);
      }
  }

  float s1[4], s2[4], thr[4];
  int i1[4], npos[4];
#pragma unroll
  for (int ni = 0; ni < 4; ++ni) {
    s1[ni] = 3.4e38f;
    s2[ni] = 3.4e38f;
    thr[ni] = 3.4e38f;
    i1[ni] = 0;
    npos[ni] = n0 + wn * 64 + ni * 16 + (lane & 15);
  }

  const _Float16* bbase = Bp + (size_t)wc * 4096 + (size_t)lane * 8;
  const int crow = wc * 16 + ((lane >> 4) << 2);  // this lane's D-frag row base
  const f32x4 z4 = (f32x4)0.f;

  f16x8 b[8];
  f32x4 accA[4], accB[4];
#pragma unroll
  for (int ks = 0; ks < 8; ++ks)
    b[ks] = *(const f16x8*)(bbase + (size_t)ks * 512);
  float4 evA = *(const float4*)(esq + crow);

  // s = 0 (no fold yet)
  CLUSTER(accA, 1)
  float4 evB = *(const float4*)(esq + 64 + crow);

  for (int s = 1; s < 63; s += 2) {
    CLUSTER(accB, s + 1)       // compute step s (odd)
    FOLD(accA, s - 1, evA)     // fold step s-1 under the MFMA pipe
    evA = *(const float4*)(esq + (s + 1) * 64 + crow);
    CLUSTER(accA, s + 2)       // compute step s+1 (even)
    FOLD(accB, s, evB)
    evB = *(const float4*)(esq + (s + 2) * 64 + crow);
  }
  // s = 63: reloads read the Bp pad (values unused)
  CLUSTER(accB, 64)
  FOLD(accA, 62, evA)
  FOLD(accB, 63, evB)

  // cross-quad merge: lanes l, l^16, l^32, l^48 share n (= output col)
  unsigned long long k1[4], k2[4];
#pragma unroll
  for (int ni = 0; ni < 4; ++ni) {
    float a1 = s1[ni], a2 = s2[ni];
    int ai1 = i1[ni];
#pragma unroll
    for (int m = 16; m <= 32; m <<= 1) {
      const float bv1 = __shfl_xor(a1, m, 64);
      const int bi1 = __shfl_xor(ai1, m, 64);
      const float bv2 = __shfl_xor(a2, m, 64);
      const float hi = fmaxf(a1, bv1);
      const bool take = (bv1 < a1) || (bv1 == a1 && bi1 < ai1);
      if (take) ai1 = bi1;
      a1 = fminf(a1, bv1);
      a2 = fminf(fminf(a2, bv2), hi);
    }
    k1[ni] = pack_key(a1, ai1);
    k2[ni] = pack_key(a2, 0);
  }
  if (lane < 16) {
#pragma unroll
    for (int ni = 0; ni < 4; ++ni) {
      const int nl = wn * 64 + ni * 16 + lane;
      mb[nl][wc][0] = k1[ni];
      mb[nl][wc][1] = k2[ni];
    }
  }
  __syncthreads();
  // finalize: top-2 over the 4 wc pairs, write idx + window flag + routing
  if (tid < 128) {
    unsigned long long m1 = ~0ull, m2 = ~0ull;
#pragma unroll
    for (int s = 0; s < 4; ++s) {
      const unsigned long long c1 = mb[tid][s][0];
      const unsigned long long c2 = mb[tid][s][1];
      if (c1 < m1) {
        m2 = m1;
        m1 = c1;
      } else if (c1 < m2) {
        m2 = c1;
      }
      if (c2 < m2) m2 = c2;  // c2 >= c1 >= m1, only competes for m2
    }
    const int n = n0 + tid;
    idx[n] = (int)(m1 & 0xFFFULL);
    const bool flag = key_score(m2) - key_score(m1) < WINDOW;
    rfin[n] = flag ? ~0ull : 0ull;
    if (flag) {
      if (cnt) {  // candidate path: rescanB consumes list
        const unsigned pos = atomicAdd(count, 1u);
        if (pos < N_VEC) list[pos] = n;
      }
      // overflow (or cand disabled) -> full-scan list; atomic read: all of
      // this block's appends to cnt[n] completed before the barrier (vmcnt(0))
      const bool toB = (cnt == nullptr) || (atomicAdd(&cnt[n], 0u) > CMAX);
      if (toB) {
        const unsigned p2 = atomicAdd(count2, 1u);
        if (p2 < N_VEC) listB[p2] = n;
      }
    }
  }
}

// ---- rescanB: exact f64 over the candidate set (frozen chain) --------------
// One wave per flagged position, 2 candidates/lane (dup-padded: atomicMin is
// idempotent). Chain per (n,k) identical to full rescan: sequential c=0..255
// f64 FMA, fl(fl(zsq - fl(2*dotf)) + esq[k]), pack_key tie -> lowest k.
__global__ __launch_bounds__(256) void rescanB_kernel(
    const float* __restrict__ zT, const float* __restrict__ cb,
    const float* __restrict__ esq, const float* __restrict__ zsq,
    const int* __restrict__ list, const unsigned int* __restrict__ count,
    const unsigned int* __restrict__ cnt,
    const unsigned short* __restrict__ candl,
    unsigned long long* __restrict__ rfin) {
  if (!candl) return;
  const int lane = threadIdx.x & 63;
  const int wv = blockIdx.x * 4 + (threadIdx.x >> 6);
  unsigned int cN = *count;
  if (cN > N_VEC) cN = N_VEC;
  for (unsigned i = wv; i < cN; i += gridDim.x * 4) {
    const int n = list[i];
    const unsigned c = cnt[n];
    if (c > CMAX) continue;  // overflow -> old full-scan rescan handles it
    const unsigned j0 = min((unsigned)(2 * lane), c - 1);
    const unsigned j1 = min((unsigned)(2 * lane + 1), c - 1);
    const int k0 = candl[(size_t)n * CMAX + j0];
    const int k1 = candl[(size_t)n * CMAX + j1];
    const float* r0 = cb + (size_t)k0 * D;
    const float* r1 = cb + (size_t)k1 * D;
    const float* zr = zT + (size_t)n * D;
    double a0 = 0., a1 = 0.;
    for (int cc = 0; cc < D; cc += 4) {
      const float4 zf = *(const float4*)(zr + cc);
      const double zx = (double)zf.x, zy = (double)zf.y;
      const double zz = (double)zf.z, zw = (double)zf.w;
      const float4 f0 = *(const float4*)(r0 + cc);
      const float4 f1 = *(const float4*)(r1 + cc);
      a0 = fma(zx, (double)f0.x, a0);
      a0 = fma(zy, (double)f0.y, a0);
      a0 = fma(zz, (double)f0.z, a0);
      a0 = fma(zw, (double)f0.w, a0);
      a1 = fma(zx, (double)f1.x, a1);
      a1 = fma(zy, (double)f1.y, a1);
      a1 = fma(zz, (double)f1.z, a1);
      a1 = fma(zw, (double)f1.w, a1);
    }
    const float zs = zsq[n];
    const float d0 =
        __fadd_rn(__fsub_rn(zs, __fmul_rn(2.0f, (float)a0)), esq[k0]);
    const float d1 =
        __fadd_rn(__fsub_rn(zs, __fmul_rn(2.0f, (float)a1)), esq[k1]);
    unsigned long long best = min(pack_key(d0, k0), pack_key(d1, k1));
#pragma unroll
    for (int off = 32; off > 0; off >>= 1)
      best = min(best, __shfl_down(best, off, 64));
    if (lane == 0) atomicMin(rfin + n, best);
  }
}

// ---- rescan (full-scan fallback, unchanged frozen chain) -------------------
__global__ __launch_bounds__(256) void rescan_kernel(
    const float* __restrict__ z, const float* __restrict__ zT,
    const float* __restrict__ cb, const float* __restrict__ esq,
    const float* __restrict__ zsq, const int* __restrict__ list,
    const unsigned int* __restrict__ count,
    unsigned long long* __restrict__ rfin) {
  __shared__ double zrow[RG][D];
  __shared__ int nloc[RG];
  __shared__ float zsv[RG];
  const int tid = threadIdx.x;
  const int lane = tid & 63;
  unsigned int cnt = *count;
  if (cnt > N_VEC) cnt = N_VEC;
  const unsigned G = (cnt + RG - 1) / RG;
  const unsigned nitems = G * (K_CODES / RSLICE);
  for (unsigned item = blockIdx.x; item < nitems; item += gridDim.x) {
    const unsigned g = item >> 4;
    const int s = item & 15;
    __syncthreads();
    if (tid < RG) {
      const unsigned r = g * RG + tid;
      const int n = (r < cnt) ? list[r] : list[cnt - 1];  // dup-pad: idempotent
      nloc[tid] = n;
      zsv[tid] = zsq[n];
    }
    __syncthreads();
    if (zT) {
      for (int i = tid; i < RG * D; i += 256) {
        const int p = i >> 8, c = i & 255;
        zrow[p][c] = (double)zT[(size_t)nloc[p] * D + c];
      }
    } else {
      for (int i = tid; i < RG * D; i += 256) {
        const int p = i >> 8, c = i & 255;
        const int n = nloc[p];
        const int b = n >> 10, hw = n & 1023;
        zrow[p][c] = (double)z[((size_t)b << 18) + ((size_t)c << 10) + hw];
      }
    }
    __syncthreads();
    const int k = s * RSLICE + tid;
    const float* row = cb + (size_t)k * D;
    double acc[RG];
#pragma unroll
    for (int p = 0; p < RG; ++p) acc[p] = 0.;
    for (int c = 0; c < D; c += 4) {
      const float4 r4 = *(const float4*)(row + c);
      const double rx = (double)r4.x, ry = (double)r4.y;
      const double rz = (double)r4.z, rw = (double)r4.w;
#pragma unroll
      for (int p = 0; p < RG; ++p) {
        const double2 za = *(const double2*)&zrow[p][c];
        const double2 zb = *(const double2*)&zrow[p][c + 2];
        double a = acc[p];
        a = fma(za.x, rx, a);
        a = fma(za.y, ry, a);
        a = fma(zb.x, rz, a);
        a = fma(zb.y, rw, a);
        acc[p] = a;
      }
    }
    const float ek = esq[k];
    unsigned long long best[RG];
#pragma unroll
    for (int p = 0; p < RG; ++p) {
      const float dotf = (float)acc[p];
      const float d = __fadd_rn(__fsub_rn(zsv[p], __fmul_rn(2.0f, dotf)), ek);
      best[p] = pack_key(d, k);
    }
#pragma unroll
    for (int p = 0; p < RG; ++p) {
#pragma unroll
      for (int off = 32; off > 0; off >>= 1)
        best[p] = min(best[p], __shfl_down(best[p], off, 64));
    }
    if (lane == 0) {
#pragma unroll
      for (int p = 0; p < RG; ++p) atomicMin(rfin + nloc[p], best[p]);
    }
  }
}

// ---- gather z_q + indices + loss -------------------------------------------
__global__ __launch_bounds__(256) void gather_kernel(
    const float* __restrict__ z, const float* __restrict__ cb,
    const int* __restrict__ idxarr, const unsigned long long* __restrict__ rfin,
    float* __restrict__ out, float* __restrict__ loss_acc,
    unsigned int* __restrict__ done) {
  const int tid = threadIdx.x;
  const int n0 = blockIdx.x * 64;
  const int hwl = tid & 63;
  const int c0 = tid >> 6;
  const int n = n0 + hwl;
  const int b = n >> 10;
  const int hw = n & 1023;
  const unsigned long long rf = rfin[n];
  const int idx = rf ? (int)(rf & 0xFFFULL) : idxarr[n];
  if (tid < 64) out[(size_t)N_ELEM + 1 + n] = (float)idx;
  const float* crow = cb + (size_t)idx * D;
  const size_t obase = ((size_t)b << 18) + hw;
  float part = 0.f;
#pragma unroll
  for (int c = c0; c < D; c += 4) {
    const float v = crow[c];
    const size_t o = obase + ((size_t)c << 10);
    const float diff = v - z[o];
    out[o] = v;
    part = fmaf(diff, diff, part);
  }
#pragma unroll
  for (int off = 32; off > 0; off >>= 1) part += __shfl_down(part, off, 64);
  __shared__ float red[4];
  if ((tid & 63) == 0) red[tid >> 6] = part;
  __syncthreads();
  if (tid == 0) {
    atomicAdd(loss_acc, red[0] + red[1] + red[2] + red[3]);
    __threadfence();
    const unsigned old = atomicAdd(done, 1u);
    if (old == gridDim.x - 1) {
      const float total = atomicAdd(loss_acc, 0.0f);
      out[N_ELEM] = 1.25f * total * (1.0f / (float)N_ELEM);
    }
  }
}

extern "C" void kernel_launch(void* const* d_in, const int* in_sizes, int n_in,
                              void* d_out, int out_size, void* d_ws,
                              size_t ws_size, hipStream_t stream) {
  const float* z = (const float*)d_in[0];
  const float* cb = (const float*)d_in[1];
  float* out = (float*)d_out;
  char* ws = (char*)d_ws;
  float* loss_acc = (float*)(ws + WS_LOSS);
  unsigned int* count = (unsigned int*)(ws + WS_COUNT);
  unsigned int* done = (unsigned int*)(ws + WS_DONE);
  unsigned int* count2 = (unsigned int*)(ws + WS_COUNT2);
  int* idx = (int*)(ws + WS_IDX);
  int* list = (int*)(ws + WS_LIST);
  float* esq = (float*)(ws + WS_ESQ);
  float* zsq = (float*)(ws + WS_ZSQ);
  _Float16* Ap = (_Float16*)(ws + WS_APACK);
  _Float16* Bp = (_Float16*)(ws + WS_BPACK);
  unsigned long long* rfin = (unsigned long long*)(ws + WS_RFIN);
  float* zT = (ws_size >= WS_NEED_ZT) ? (float*)(ws + WS_ZT) : nullptr;
  const bool canduse = (ws_size >= WS_NEED_CAND) && (zT != nullptr);
  unsigned int* cnt = canduse ? (unsigned int*)(ws + WS_CNT) : nullptr;
  unsigned short* candl = canduse ? (unsigned short*)(ws + WS_CANDL) : nullptr;
  int* listB = canduse ? (int*)(ws + WS_LISTB) : list;

  hipMemsetAsync(ws, 0, 256, stream);
  if (canduse) hipMemsetAsync(ws + WS_CNT, 0, (size_t)N_VEC * 4, stream);
  prep_kernel<<<PREP_BLOCKS, 256, 0, stream>>>(z, cb, esq, zsq, Ap, Bp, zT);
  dist2_kernel<<<N_VEC / 128, 512, 0, stream>>>(Ap, Bp, esq, idx, list, count,
                                                rfin, cnt, candl, listB,
                                                count2);
  rescanB_kernel<<<512, 256, 0, stream>>>(zT, cb, esq, zsq, list, count, cnt,
                                          candl, rfin);
  rescan_kernel<<<2048, 256, 0, stream>>>(z, zT, cb, esq, zsq, listB, count2,
                                          rfin);
  gather_kernel<<<N_VEC / 64, 256, 0, stream>>>(z, cb, idx, rfin, out,
                                                loss_acc, done);
}

// Round 7
// 329.416 us; speedup vs baseline: 2.1013x; 2.1013x over previous
//
#include <hip/hip_runtime.h>

#define K_CODES 4096
#define D 256
#define N_VEC 32768
#define N_ELEM 8388608   // 32*256*32*32
#define WINDOW 3.5e-4f
#define WINDOW_C 5.25e-4f  // top-4 certification margin (1.5x WINDOW)
#define RG 8             // rescan positions per group (fallback)
#define RSLICE 256       // rescan codes per slice (fallback)

typedef _Float16 f16x8 __attribute__((ext_vector_type(8)));
typedef float f32x4 __attribute__((ext_vector_type(4)));

// ws layout (bytes)
#define WS_LOSS 0
#define WS_COUNT 8
#define WS_DONE 16
#define WS_COUNT2 24
#define WS_IDX 256
#define WS_LIST (WS_IDX + N_VEC * 4)
#define WS_ESQ (WS_LIST + N_VEC * 4)
#define WS_ZSQ (WS_ESQ + K_CODES * 4)
#define WS_APACK (WS_ZSQ + N_VEC * 4)                    // f16 frag-order z
#define WS_BPACK (WS_APACK + (size_t)N_VEC * 256 * 2)    // f16 frag-order cb
// Bp padded +64KB: pipelined reload reads one step (32KB) past the end
#define WS_RFIN (WS_BPACK + (size_t)K_CODES * 256 * 2 + 65536)
#define WS_ZT (WS_RFIN + (size_t)N_VEC * 8)              // f32 z^T [N_VEC][D]
#define WS_NEED_ZT (WS_ZT + (size_t)N_VEC * D * 4)
#define WS_CAND4 WS_NEED_ZT                              // u64[N_VEC]: 4x u16
#define WS_LISTB (WS_CAND4 + (size_t)N_VEC * 8)
#define WS_NEED_CAND (WS_LISTB + (size_t)N_VEC * 4)

// prep fusion block regions
#define PREP_PZ 4096    // pack_z2: 1M frag-slots / 256
#define PREP_PCB 512    // pack_cb2: 128K frag-slots / 256
#define PREP_ESQ 1024
#define PREP_ZSQ 128
#define PREP_BLOCKS (PREP_PZ + PREP_PCB + PREP_ESQ + PREP_ZSQ)

__device__ __forceinline__ unsigned long long pack_key(float s, int idx) {
  const unsigned u = __float_as_uint(s);
  const unsigned mk = (u & 0x80000000u) ? ~u : (u | 0x80000000u);
  return ((unsigned long long)mk << 12) | (unsigned long long)(unsigned)idx;
}
__device__ __forceinline__ float key_score(unsigned long long k) {
  const unsigned mk = (unsigned)(k >> 12);
  const unsigned u = (mk & 0x80000000u) ? (mk & 0x7fffffffu) : ~mk;
  return __uint_as_float(u);
}

// opaque identity: result can't be rematerialized -> forces register residency
__device__ __forceinline__ void pin_frag(f16x8& v) {
  asm volatile("" : "+v"(v));
}

// insert key x into ascending-sorted K[0..3], keep 4 smallest
__device__ __forceinline__ void ins4(unsigned long long K[4],
                                     unsigned long long x) {
  const bool b0 = x < K[0];
  const bool b1 = x < K[1];
  const bool b2 = x < K[2];
  const bool b3 = x < K[3];
  K[3] = b2 ? K[2] : (b3 ? x : K[3]);
  K[2] = b1 ? K[1] : (b2 ? x : K[2]);
  K[1] = b0 ? K[0] : (b1 ? x : K[1]);
  K[0] = b0 ? x : K[0];
}

// ---- e_sq body: fp32-squared terms, f64 accumulate, f32 round (frozen) -----
__device__ void esq_body(int bx, const float* __restrict__ cb,
                         float* __restrict__ esq) {
  const int lane = threadIdx.x & 63;
  const int k = bx * 4 + (threadIdx.x >> 6);
  const float* row = cb + (size_t)k * D;
  double s = 0.;
#pragma unroll
  for (int j = 0; j < 4; ++j) {
    const float v = row[lane + 64 * j];
    s += (double)__fmul_rn(v, v);
  }
#pragma unroll
  for (int off = 32; off > 0; off >>= 1) s += __shfl_down(s, off, 64);
  if (lane == 0) esq[k] = (float)s;
}

// ---- z_sq body (frozen: deterministic per-position order) ------------------
__device__ void zsq_body(int bx, const float* __restrict__ z,
                         float* __restrict__ zsq) {
  const int n = bx * 256 + threadIdx.x;
  const int b = n >> 10;
  const int hw = n & 1023;
  const float* p = z + ((size_t)b << 18) + hw;
  double a0 = 0., a1 = 0., a2 = 0., a3 = 0.;
  for (int c = 0; c < D; c += 4) {
    const float v0 = p[(size_t)(c + 0) << 10];
    const float v1 = p[(size_t)(c + 1) << 10];
    const float v2 = p[(size_t)(c + 2) << 10];
    const float v3 = p[(size_t)(c + 3) << 10];
    a0 += (double)__fmul_rn(v0, v0);
    a1 += (double)__fmul_rn(v1, v1);
    a2 += (double)__fmul_rn(v2, v2);
    a3 += (double)__fmul_rn(v3, v3);
  }
  zsq[n] = (float)((a0 + a1) + (a2 + a3));
}

// ---- pack z -> MFMA-fragment order (+ f32 transpose zT) --------------------
__device__ void pack_z2_body(int bx, const float* __restrict__ z,
                             _Float16* __restrict__ Ap,
                             float* __restrict__ zT) {
  const int t = bx * 256 + threadIdx.x;   // [0, 1048576)
  const int lane = t & 63;
  const int fid = t >> 6;                 // [0, 16384)
  const int ks = fid & 7;
  const int grp = fid >> 3;               // 16-row group
  const int n = grp * 16 + (lane & 15);
  const int d = ks * 32 + ((lane >> 4) << 3);
  const int b = n >> 10, hw = n & 1023;
  const float* p = z + ((size_t)b << 18) + ((size_t)d << 10) + hw;
  float v[8];
  f16x8 H;
#pragma unroll
  for (int j = 0; j < 8; ++j) {
    v[j] = p[(size_t)j << 10];
    H[j] = (_Float16)v[j];
  }
  *(f16x8*)(Ap + (size_t)t * 8) = H;
  if (zT) {  // same float values, transposed layout -> coalesced reads later
    float4* o = (float4*)(zT + (size_t)n * D + d);
    o[0] = make_float4(v[0], v[1], v[2], v[3]);
    o[1] = make_float4(v[4], v[5], v[6], v[7]);
  }
}

// ---- pack cb -> MFMA-fragment order, f16(256*e) ----------------------------
__device__ void pack_cb2_body(int bx, const float* __restrict__ cb,
                              _Float16* __restrict__ Bp) {
  const int t = bx * 256 + threadIdx.x;   // [0, 131072)
  const int lane = t & 63;
  const int fid = t >> 6;                 // [0, 2048)
  const int ks = fid & 7;
  const int grp = fid >> 3;               // [0, 256)
  const int k = grp * 16 + (lane & 15);
  const int d = ks * 32 + ((lane >> 4) << 3);
  const float* p = cb + (size_t)k * D + d;
  f16x8 H;
#pragma unroll
  for (int j = 0; j < 8; ++j) H[j] = (_Float16)(p[j] * 256.f);
  *(f16x8*)(Bp + (size_t)t * 8) = H;
}

// ---- fused prep ------------------------------------------------------------
__global__ __launch_bounds__(256) void prep_kernel(
    const float* __restrict__ z, const float* __restrict__ cb,
    float* __restrict__ esq, float* __restrict__ zsq,
    _Float16* __restrict__ Ap, _Float16* __restrict__ Bp,
    float* __restrict__ zT) {
  const int b = blockIdx.x;
  if (b < PREP_PZ) {
    pack_z2_body(b, z, Ap, zT);
  } else if (b < PREP_PZ + PREP_PCB) {
    pack_cb2_body(b - PREP_PZ, cb, Bp);
  } else if (b < PREP_PZ + PREP_PCB + PREP_ESQ) {
    esq_body(b - PREP_PZ - PREP_PCB, cb, esq);
  } else {
    zsq_body(b - PREP_PZ - PREP_PCB - PREP_ESQ, z, zsq);
  }
}

// ---- barrier-free MFMA distance + TOP-4 ------------------------------------
// R5-proven core (no sleep): 256 blocks x 128 n-rows, 8 waves (wn x wc),
// A pinned in VGPRs (a[4][8]), B single 8-frag buffer with in-cluster reload.
// Fold keeps a sorted TOP-4 (value,idx) per chain via guarded branchless
// insert (strict < -> ties keep lower code; s1/s2 stream == old kernel, so
// idx + window-flag are bit-identical). Epilogue merges via packed keys
// (pack_key is monotone with the idx tie-break). For flagged positions:
// if coarse(K3)-coarse(K0) >= WINDOW_C, the design's own invariant
// (|coarse-exact| <= WINDOW/2, already trusted for every unflagged position)
// proves the exact winner (ties included) is in {K0..K3} -> rescanB does f64
// on 4 candidates only. Else -> listB -> unchanged full-scan rescan.
__global__ __launch_bounds__(512, 2) void dist2_kernel(
    const _Float16* __restrict__ Ap, const _Float16* __restrict__ Bp,
    const float* __restrict__ esq, int* __restrict__ idx,
    int* __restrict__ list, unsigned int* __restrict__ count,
    unsigned long long* __restrict__ rfin, unsigned long long* __restrict__ cand4,
    int* __restrict__ listB, unsigned int* __restrict__ count2) {
  __shared__ unsigned long long mb[128][4][4];  // 16 KB epilogue merge buffer
  const int tid = threadIdx.x;
  const int lane = tid & 63;
  const int w = tid >> 6;
  const int wn = w >> 2;   // n-group  (0..1)
  const int wc = w & 3;    // code-col (0..3)
  const int n0 = blockIdx.x * 128;

  // A frags: this wave's 64 n-rows x full K=256 -> 32 x f16x8 = 128 VGPRs
  f16x8 a[4][8];
  {
    const _Float16* ab =
        Ap + (size_t)((n0 + wn * 64) >> 4) * 4096 + (size_t)lane * 8;
#pragma unroll
    for (int ni = 0; ni < 4; ++ni)
#pragma unroll
      for (int ks = 0; ks < 8; ++ks) {
        a[ni][ks] = *(const f16x8*)(ab + (size_t)(ni * 8 + ks) * 512);
        pin_frag(a[ni][ks]);
      }
  }

  float sv[4][4];
  int iv[4][4];
#pragma unroll
  for (int ni = 0; ni < 4; ++ni) {
    sv[ni][0] = 3.4e38f; sv[ni][1] = 3.4e38f;
    sv[ni][2] = 3.4e38f; sv[ni][3] = 3.4e38f;
    iv[ni][0] = 0; iv[ni][1] = 0; iv[ni][2] = 0; iv[ni][3] = 0;
  }

  const _Float16* bbase = Bp + (size_t)wc * 4096 + (size_t)lane * 8;
  const int crow = wc * 16 + ((lane >> 4) << 2);  // this lane's D-frag row base
  const f32x4 z4 = (f32x4)0.f;

  f16x8 b[8];
#pragma unroll
  for (int ks = 0; ks < 8; ++ks)
    b[ks] = *(const f16x8*)(bbase + (size_t)ks * 512);

  for (int t = 0; t < 64; ++t) {
    const float4 e4 = *(const float4*)(esq + t * 64 + crow);
    f32x4 acc0, acc1, acc2, acc3;
    __builtin_amdgcn_s_setprio(1);
#pragma unroll
    for (int ks = 0; ks < 8; ++ks) {
      acc0 = __builtin_amdgcn_mfma_f32_16x16x32_f16(b[ks], a[0][ks],
                                                    ks ? acc0 : z4, 0, 0, 0);
      acc1 = __builtin_amdgcn_mfma_f32_16x16x32_f16(b[ks], a[1][ks],
                                                    ks ? acc1 : z4, 0, 0, 0);
      acc2 = __builtin_amdgcn_mfma_f32_16x16x32_f16(b[ks], a[2][ks],
                                                    ks ? acc2 : z4, 0, 0, 0);
      acc3 = __builtin_amdgcn_mfma_f32_16x16x32_f16(b[ks], a[3][ks],
                                                    ks ? acc3 : z4, 0, 0, 0);
      // reload for step t+1 (t=63 reads the Bp pad; values unused)
      b[ks] = *(const f16x8*)(bbase + (size_t)(t + 1) * 16384 + ks * 512);
    }
    __builtin_amdgcn_s_setprio(0);
    const int cb0 = t * 64 + crow;
    const float ev[4] = {e4.x, e4.y, e4.z, e4.w};
    f32x4 accv[4] = {acc0, acc1, acc2, acc3};
#pragma unroll
    for (int r = 0; r < 4; ++r) {
      const int code = cb0 + r;
#pragma unroll
      for (int ni = 0; ni < 4; ++ni) {
        const float s = fmaf(accv[ni][r], -0.0078125f, ev[r]);
        if (s < sv[ni][3]) {  // rare path: guarded branchless sorted insert
          const bool b0 = s < sv[ni][0];
          const bool b1 = s < sv[ni][1];
          const bool b2 = s < sv[ni][2];
          sv[ni][3] = b2 ? sv[ni][2] : s;
          iv[ni][3] = b2 ? iv[ni][2] : code;
          sv[ni][2] = b1 ? sv[ni][1] : (b2 ? s : sv[ni][2]);
          iv[ni][2] = b1 ? iv[ni][1] : (b2 ? code : iv[ni][2]);
          sv[ni][1] = b0 ? sv[ni][0] : (b1 ? s : sv[ni][1]);
          iv[ni][1] = b0 ? iv[ni][0] : (b1 ? code : iv[ni][1]);
          sv[ni][0] = b0 ? s : sv[ni][0];
          iv[ni][0] = b0 ? code : iv[ni][0];
        }
      }
    }
  }

  // cross-quad merge via packed keys (monotone in (score, idx))
#pragma unroll
  for (int ni = 0; ni < 4; ++ni) {
    unsigned long long K[4];
    K[0] = pack_key(sv[ni][0], iv[ni][0]);
    K[1] = pack_key(sv[ni][1], iv[ni][1]);
    K[2] = pack_key(sv[ni][2], iv[ni][2]);
    K[3] = pack_key(sv[ni][3], iv[ni][3]);
#pragma unroll
    for (int m = 16; m <= 32; m <<= 1) {
      const unsigned long long o0 = __shfl_xor(K[0], m, 64);
      const unsigned long long o1 = __shfl_xor(K[1], m, 64);
      const unsigned long long o2 = __shfl_xor(K[2], m, 64);
      const unsigned long long o3 = __shfl_xor(K[3], m, 64);
      ins4(K, o0);
      ins4(K, o1);
      ins4(K, o2);
      ins4(K, o3);
    }
    if (lane < 16) {
      const int nl = wn * 64 + ni * 16 + lane;
      mb[nl][wc][0] = K[0];
      mb[nl][wc][1] = K[1];
      mb[nl][wc][2] = K[2];
      mb[nl][wc][3] = K[3];
    }
  }
  __syncthreads();
  // finalize: top-4 over the 4 wc lists; write idx, flag, candidates
  if (tid < 128) {
    unsigned long long K[4] = {mb[tid][0][0], mb[tid][0][1], mb[tid][0][2],
                               mb[tid][0][3]};
#pragma unroll
    for (int s = 1; s < 4; ++s) {
      ins4(K, mb[tid][s][0]);
      ins4(K, mb[tid][s][1]);
      ins4(K, mb[tid][s][2]);
      ins4(K, mb[tid][s][3]);
    }
    const int n = n0 + tid;
    idx[n] = (int)(K[0] & 0xFFFULL);
    const float sc0 = key_score(K[0]);
    const bool flag = key_score(K[1]) - sc0 < WINDOW;
    rfin[n] = flag ? ~0ull : 0ull;
    if (flag) {
      if (cand4 && (key_score(K[3]) - sc0 >= WINDOW_C)) {
        cand4[n] = (K[0] & 0xFFFULL) | ((K[1] & 0xFFFULL) << 16) |
                   ((K[2] & 0xFFFULL) << 32) | ((K[3] & 0xFFFULL) << 48);
        const unsigned pos = atomicAdd(count, 1u);
        if (pos < N_VEC) list[pos] = n;
      } else {
        const unsigned p2 = atomicAdd(count2, 1u);
        if (p2 < N_VEC) listB[p2] = n;
      }
    }
  }
}

// ---- rescanB: exact f64 on the 4 certified candidates (frozen chain) -------
// thread = (flagged position i, candidate j). Chain per (n,k) identical to
// the full rescan: sequential c=0..255 f64 fma in c,c+1,c+2,c+3 order;
// d = fl(fl(zsq - fl(2*(float)dot)) + esq[k]); pack_key; min; atomicMin.
__global__ __launch_bounds__(256) void rescanB_kernel(
    const float* __restrict__ zT, const float* __restrict__ cb,
    const float* __restrict__ esq, const float* __restrict__ zsq,
    const int* __restrict__ list, const unsigned int* __restrict__ count,
    const unsigned long long* __restrict__ cand4,
    unsigned long long* __restrict__ rfin) {
  if (!cand4) return;
  unsigned int cN = *count;
  if (cN > N_VEC) cN = N_VEC;
  const int tid = threadIdx.x;
  const int j = tid & 3;
  for (unsigned i = blockIdx.x * 64 + (tid >> 2); i < cN; i += gridDim.x * 64) {
    const int n = list[i];
    const int k = (int)((cand4[n] >> (16 * j)) & 0xFFFULL);
    const float* zr = zT + (size_t)n * D;
    const float* row = cb + (size_t)k * D;
    double a = 0.;
    for (int c = 0; c < D; c += 4) {
      const float4 zf = *(const float4*)(zr + c);
      const float4 r4 = *(const float4*)(row + c);
      a = fma((double)zf.x, (double)r4.x, a);
      a = fma((double)zf.y, (double)r4.y, a);
      a = fma((double)zf.z, (double)r4.z, a);
      a = fma((double)zf.w, (double)r4.w, a);
    }
    const float d =
        __fadd_rn(__fsub_rn(zsq[n], __fmul_rn(2.0f, (float)a)), esq[k]);
    unsigned long long best = pack_key(d, k);
    best = min(best, __shfl_xor(best, 1, 64));
    best = min(best, __shfl_xor(best, 2, 64));
    if (j == 0) atomicMin(rfin + n, best);
  }
}

// ---- rescan (full-scan fallback for uncertified positions; frozen) ---------
__global__ __launch_bounds__(256) void rescan_kernel(
    const float* __restrict__ z, const float* __restrict__ zT,
    const float* __restrict__ cb, const float* __restrict__ esq,
    const float* __restrict__ zsq, const int* __restrict__ list,
    const unsigned int* __restrict__ count,
    unsigned long long* __restrict__ rfin) {
  __shared__ double zrow[RG][D];
  __shared__ int nloc[RG];
  __shared__ float zsv[RG];
  const int tid = threadIdx.x;
  const int lane = tid & 63;
  unsigned int cnt = *count;
  if (cnt > N_VEC) cnt = N_VEC;
  const unsigned G = (cnt + RG - 1) / RG;
  const unsigned nitems = G * (K_CODES / RSLICE);
  for (unsigned item = blockIdx.x; item < nitems; item += gridDim.x) {
    const unsigned g = item >> 4;
    const int s = item & 15;
    __syncthreads();
    if (tid < RG) {
      const unsigned r = g * RG + tid;
      const int n = (r < cnt) ? list[r] : list[cnt - 1];  // dup-pad: idempotent
      nloc[tid] = n;
      zsv[tid] = zsq[n];
    }
    __syncthreads();
    if (zT) {
      for (int i = tid; i < RG * D; i += 256) {
        const int p = i >> 8, c = i & 255;
        zrow[p][c] = (double)zT[(size_t)nloc[p] * D + c];
      }
    } else {
      for (int i = tid; i < RG * D; i += 256) {
        const int p = i >> 8, c = i & 255;
        const int n = nloc[p];
        const int b = n >> 10, hw = n & 1023;
        zrow[p][c] = (double)z[((size_t)b << 18) + ((size_t)c << 10) + hw];
      }
    }
    __syncthreads();
    const int k = s * RSLICE + tid;
    const float* row = cb + (size_t)k * D;
    double acc[RG];
#pragma unroll
    for (int p = 0; p < RG; ++p) acc[p] = 0.;
    for (int c = 0; c < D; c += 4) {
      const float4 r4 = *(const float4*)(row + c);
      const double rx = (double)r4.x, ry = (double)r4.y;
      const double rz = (double)r4.z, rw = (double)r4.w;
#pragma unroll
      for (int p = 0; p < RG; ++p) {
        const double2 za = *(const double2*)&zrow[p][c];
        const double2 zb = *(const double2*)&zrow[p][c + 2];
        double a = acc[p];
        a = fma(za.x, rx, a);
        a = fma(za.y, ry, a);
        a = fma(zb.x, rz, a);
        a = fma(zb.y, rw, a);
        acc[p] = a;
      }
    }
    const float ek = esq[k];
    unsigned long long best[RG];
#pragma unroll
    for (int p = 0; p < RG; ++p) {
      const float dotf = (float)acc[p];
      const float d = __fadd_rn(__fsub_rn(zsv[p], __fmul_rn(2.0f, dotf)), ek);
      best[p] = pack_key(d, k);
    }
#pragma unroll
    for (int p = 0; p < RG; ++p) {
#pragma unroll
      for (int off = 32; off > 0; off >>= 1)
        best[p] = min(best[p], __shfl_down(best[p], off, 64));
    }
    if (lane == 0) {
#pragma unroll
      for (int p = 0; p < RG; ++p) atomicMin(rfin + nloc[p], best[p]);
    }
  }
}

// ---- gather z_q + indices + loss (cb reads float4-ized) --------------------
__global__ __launch_bounds__(256) void gather_kernel(
    const float* __restrict__ z, const float* __restrict__ cb,
    const int* __restrict__ idxarr, const unsigned long long* __restrict__ rfin,
    float* __restrict__ out, float* __restrict__ loss_acc,
    unsigned int* __restrict__ done) {
  const int tid = threadIdx.x;
  const int n0 = blockIdx.x * 64;
  const int hwl = tid & 63;
  const int cq = tid >> 6;  // c block [cq*64, cq*64+64)
  const int n = n0 + hwl;
  const int b = n >> 10;
  const int hw = n & 1023;
  const unsigned long long rf = rfin[n];
  const int idx = rf ? (int)(rf & 0xFFFULL) : idxarr[n];
  if (tid < 64) out[(size_t)N_ELEM + 1 + n] = (float)idx;
  const float* crow = cb + (size_t)idx * D;
  const size_t obase = ((size_t)b << 18) + hw;
  float part = 0.f;
#pragma unroll
  for (int j = 0; j < 16; ++j) {
    const int c = cq * 64 + j * 4;
    const float4 v4 = *(const float4*)(crow + c);
    const size_t o = obase + ((size_t)c << 10);
    const float d0 = v4.x - z[o];
    const float d1 = v4.y - z[o + 1024];
    const float d2 = v4.z - z[o + 2048];
    const float d3 = v4.w - z[o + 3072];
    out[o] = v4.x;
    out[o + 1024] = v4.y;
    out[o + 2048] = v4.z;
    out[o + 3072] = v4.w;
    part = fmaf(d0, d0, part);
    part = fmaf(d1, d1, part);
    part = fmaf(d2, d2, part);
    part = fmaf(d3, d3, part);
  }
#pragma unroll
  for (int off = 32; off > 0; off >>= 1) part += __shfl_down(part, off, 64);
  __shared__ float red[4];
  if ((tid & 63) == 0) red[tid >> 6] = part;
  __syncthreads();
  if (tid == 0) {
    atomicAdd(loss_acc, red[0] + red[1] + red[2] + red[3]);
    __threadfence();
    const unsigned old = atomicAdd(done, 1u);
    if (old == gridDim.x - 1) {
      const float total = atomicAdd(loss_acc, 0.0f);
      out[N_ELEM] = 1.25f * total * (1.0f / (float)N_ELEM);
    }
  }
}

extern "C" void kernel_launch(void* const* d_in, const int* in_sizes, int n_in,
                              void* d_out, int out_size, void* d_ws,
                              size_t ws_size, hipStream_t stream) {
  const float* z = (const float*)d_in[0];
  const float* cb = (const float*)d_in[1];
  float* out = (float*)d_out;
  char* ws = (char*)d_ws;
  float* loss_acc = (float*)(ws + WS_LOSS);
  unsigned int* count = (unsigned int*)(ws + WS_COUNT);
  unsigned int* done = (unsigned int*)(ws + WS_DONE);
  unsigned int* count2 = (unsigned int*)(ws + WS_COUNT2);
  int* idx = (int*)(ws + WS_IDX);
  int* list = (int*)(ws + WS_LIST);
  float* esq = (float*)(ws + WS_ESQ);
  float* zsq = (float*)(ws + WS_ZSQ);
  _Float16* Ap = (_Float16*)(ws + WS_APACK);
  _Float16* Bp = (_Float16*)(ws + WS_BPACK);
  unsigned long long* rfin = (unsigned long long*)(ws + WS_RFIN);
  float* zT = (ws_size >= WS_NEED_ZT) ? (float*)(ws + WS_ZT) : nullptr;
  const bool canduse = (ws_size >= WS_NEED_CAND) && (zT != nullptr);
  unsigned long long* cand4 =
      canduse ? (unsigned long long*)(ws + WS_CAND4) : nullptr;
  int* listB = canduse ? (int*)(ws + WS_LISTB) : list;
  unsigned int* cntB = canduse ? count2 : count2;  // always count2

  hipMemsetAsync(ws, 0, 256, stream);
  prep_kernel<<<PREP_BLOCKS, 256, 0, stream>>>(z, cb, esq, zsq, Ap, Bp, zT);
  dist2_kernel<<<N_VEC / 128, 512, 0, stream>>>(Ap, Bp, esq, idx, list, count,
                                                rfin, cand4, listB, cntB);
  rescanB_kernel<<<512, 256, 0, stream>>>(zT, cb, esq, zsq, list, count, cand4,
                                          rfin);
  rescan_kernel<<<2048, 256, 0, stream>>>(z, zT, cb, esq, zsq, listB, cntB,
                                          rfin);
  gather_kernel<<<N_VEC / 64, 256, 0, stream>>>(z, cb, idx, rfin, out,
                                                loss_acc, done);
}

// Round 8
// 271.289 us; speedup vs baseline: 2.5516x; 1.2143x over previous
//
#include <hip/hip_runtime.h>

#define K_CODES 4096
#define D 256
#define N_VEC 32768
#define N_ELEM 8388608   // 32*256*32*32
#define WINDOW 3.5e-4f
#define WINDOW_C 5.25e-4f  // certification margin (1.5x WINDOW, needs > W)
#define RG 8             // rescan positions per group (fallback)
#define RSLICE 256       // rescan codes per slice (fallback)

typedef _Float16 f16x8 __attribute__((ext_vector_type(8)));
typedef float f32x4 __attribute__((ext_vector_type(4)));

// ws layout (bytes)
#define WS_LOSS 0
#define WS_COUNT 8
#define WS_DONE 16
#define WS_COUNT2 24
#define WS_IDX 256
#define WS_LIST (WS_IDX + N_VEC * 4)
#define WS_ESQ (WS_LIST + N_VEC * 4)
#define WS_ZSQ (WS_ESQ + K_CODES * 4)
#define WS_APACK (WS_ZSQ + N_VEC * 4)                    // f16 frag-order z
#define WS_BPACK (WS_APACK + (size_t)N_VEC * 256 * 2)    // f16 frag-order cb
// Bp padded +64KB: pipelined reload reads one step (32KB) past the end
#define WS_RFIN (WS_BPACK + (size_t)K_CODES * 256 * 2 + 65536)
#define WS_ZT (WS_RFIN + (size_t)N_VEC * 8)              // f32 z^T [N_VEC][D]
#define WS_NEED_ZT (WS_ZT + (size_t)N_VEC * D * 4)
#define WS_CAND4 WS_NEED_ZT                              // u64[N_VEC]: 2x u16
#define WS_LISTB (WS_CAND4 + (size_t)N_VEC * 8)
#define WS_NEED_CAND (WS_LISTB + (size_t)N_VEC * 4)

// prep fusion block regions
#define PREP_PZ 4096    // pack_z2: 1M frag-slots / 256
#define PREP_PCB 512    // pack_cb2: 128K frag-slots / 256
#define PREP_ESQ 1024
#define PREP_ZSQ 128
#define PREP_BLOCKS (PREP_PZ + PREP_PCB + PREP_ESQ + PREP_ZSQ)

__device__ __forceinline__ unsigned long long pack_key(float s, int idx) {
  const unsigned u = __float_as_uint(s);
  const unsigned mk = (u & 0x80000000u) ? ~u : (u | 0x80000000u);
  return ((unsigned long long)mk << 12) | (unsigned long long)(unsigned)idx;
}
__device__ __forceinline__ float key_score(unsigned long long k) {
  const unsigned mk = (unsigned)(k >> 12);
  const unsigned u = (mk & 0x80000000u) ? (mk & 0x7fffffffu) : ~mk;
  return __uint_as_float(u);
}

// opaque identity: result can't be rematerialized -> forces register residency
__device__ __forceinline__ void pin_frag(f16x8& v) {
  asm volatile("" : "+v"(v));
}

// insert key x into ascending-sorted (K0,K1,K2), keep 3 smallest (branchless)
__device__ __forceinline__ void ins3(unsigned long long& K0,
                                     unsigned long long& K1,
                                     unsigned long long& K2,
                                     unsigned long long x) {
  const bool b0 = x < K0;
  const bool b1 = x < K1;
  const bool b2 = x < K2;
  K2 = b1 ? K1 : (b2 ? x : K2);
  K1 = b0 ? K0 : (b1 ? x : K1);
  K0 = b0 ? x : K0;
}

// ---- e_sq body: fp32-squared terms, f64 accumulate, f32 round (frozen) -----
__device__ void esq_body(int bx, const float* __restrict__ cb,
                         float* __restrict__ esq) {
  const int lane = threadIdx.x & 63;
  const int k = bx * 4 + (threadIdx.x >> 6);
  const float* row = cb + (size_t)k * D;
  double s = 0.;
#pragma unroll
  for (int j = 0; j < 4; ++j) {
    const float v = row[lane + 64 * j];
    s += (double)__fmul_rn(v, v);
  }
#pragma unroll
  for (int off = 32; off > 0; off >>= 1) s += __shfl_down(s, off, 64);
  if (lane == 0) esq[k] = (float)s;
}

// ---- z_sq body (frozen: deterministic per-position order) ------------------
__device__ void zsq_body(int bx, const float* __restrict__ z,
                         float* __restrict__ zsq) {
  const int n = bx * 256 + threadIdx.x;
  const int b = n >> 10;
  const int hw = n & 1023;
  const float* p = z + ((size_t)b << 18) + hw;
  double a0 = 0., a1 = 0., a2 = 0., a3 = 0.;
  for (int c = 0; c < D; c += 4) {
    const float v0 = p[(size_t)(c + 0) << 10];
    const float v1 = p[(size_t)(c + 1) << 10];
    const float v2 = p[(size_t)(c + 2) << 10];
    const float v3 = p[(size_t)(c + 3) << 10];
    a0 += (double)__fmul_rn(v0, v0);
    a1 += (double)__fmul_rn(v1, v1);
    a2 += (double)__fmul_rn(v2, v2);
    a3 += (double)__fmul_rn(v3, v3);
  }
  zsq[n] = (float)((a0 + a1) + (a2 + a3));
}

// ---- pack z -> MFMA-fragment order (+ f32 transpose zT) --------------------
__device__ void pack_z2_body(int bx, const float* __restrict__ z,
                             _Float16* __restrict__ Ap,
                             float* __restrict__ zT) {
  const int t = bx * 256 + threadIdx.x;   // [0, 1048576)
  const int lane = t & 63;
  const int fid = t >> 6;                 // [0, 16384)
  const int ks = fid & 7;
  const int grp = fid >> 3;               // 16-row group
  const int n = grp * 16 + (lane & 15);
  const int d = ks * 32 + ((lane >> 4) << 3);
  const int b = n >> 10, hw = n & 1023;
  const float* p = z + ((size_t)b << 18) + ((size_t)d << 10) + hw;
  float v[8];
  f16x8 H;
#pragma unroll
  for (int j = 0; j < 8; ++j) {
    v[j] = p[(size_t)j << 10];
    H[j] = (_Float16)v[j];
  }
  *(f16x8*)(Ap + (size_t)t * 8) = H;
  if (zT) {  // same float values, transposed layout -> coalesced reads later
    float4* o = (float4*)(zT + (size_t)n * D + d);
    o[0] = make_float4(v[0], v[1], v[2], v[3]);
    o[1] = make_float4(v[4], v[5], v[6], v[7]);
  }
}

// ---- pack cb -> MFMA-fragment order, f16(256*e) ----------------------------
__device__ void pack_cb2_body(int bx, const float* __restrict__ cb,
                              _Float16* __restrict__ Bp) {
  const int t = bx * 256 + threadIdx.x;   // [0, 131072)
  const int lane = t & 63;
  const int fid = t >> 6;                 // [0, 2048)
  const int ks = fid & 7;
  const int grp = fid >> 3;               // [0, 256)
  const int k = grp * 16 + (lane & 15);
  const int d = ks * 32 + ((lane >> 4) << 3);
  const float* p = cb + (size_t)k * D + d;
  f16x8 H;
#pragma unroll
  for (int j = 0; j < 8; ++j) H[j] = (_Float16)(p[j] * 256.f);
  *(f16x8*)(Bp + (size_t)t * 8) = H;
}

// ---- fused prep ------------------------------------------------------------
__global__ __launch_bounds__(256) void prep_kernel(
    const float* __restrict__ z, const float* __restrict__ cb,
    float* __restrict__ esq, float* __restrict__ zsq,
    _Float16* __restrict__ Ap, _Float16* __restrict__ Bp,
    float* __restrict__ zT) {
  const int b = blockIdx.x;
  if (b < PREP_PZ) {
    pack_z2_body(b, z, Ap, zT);
  } else if (b < PREP_PZ + PREP_PCB) {
    pack_cb2_body(b - PREP_PZ, cb, Bp);
  } else if (b < PREP_PZ + PREP_PCB + PREP_ESQ) {
    esq_body(b - PREP_PZ - PREP_PCB, cb, esq);
  } else {
    zsq_body(b - PREP_PZ - PREP_PCB - PREP_ESQ, z, zsq);
  }
}

// ---- barrier-free MFMA distance + branchless top-3 -------------------------
// R5-proven core: 256 blocks x 128 n-rows, 8 waves (wn x wc), A pinned in
// VGPRs (a[4][8]), B single 8-frag buffer with in-cluster reload.
// Fold tracks top-3 VALUES + top-2 INDICES, fully branchless (11 VALU/score;
// R7's guarded branch insert serialized wave issue -> 186us, reverted).
// s1/s2 value streams identical to R5 -> idx + window-flag bit-identical.
// Certification: flagged n with score(K2)-score(K0) >= WINDOW_C (=1.5W)
// proves (|coarse-exact| <= W/2 invariant, already trusted for unflagged)
// that every exact winner/tie is in {K0,K1}: excluded k has
// exact(k) >= coarse(k)-W/2 >= s0+1.5W-W/2 = s0+W > s0+W/2 >= exact(K0).
// -> rescanB does the frozen f64 chain on 2 candidates. Else -> full scan.
__global__ __launch_bounds__(512, 2) void dist2_kernel(
    const _Float16* __restrict__ Ap, const _Float16* __restrict__ Bp,
    const float* __restrict__ esq, int* __restrict__ idx,
    int* __restrict__ list, unsigned int* __restrict__ count,
    unsigned long long* __restrict__ rfin,
    unsigned long long* __restrict__ cand4, int* __restrict__ listB,
    unsigned int* __restrict__ count2) {
  __shared__ unsigned long long mb[128][4][3];  // 12 KB epilogue merge buffer
  const int tid = threadIdx.x;
  const int lane = tid & 63;
  const int w = tid >> 6;
  const int wn = w >> 2;   // n-group  (0..1)
  const int wc = w & 3;    // code-col (0..3)
  const int n0 = blockIdx.x * 128;

  // A frags: this wave's 64 n-rows x full K=256 -> 32 x f16x8 = 128 VGPRs
  f16x8 a[4][8];
  {
    const _Float16* ab =
        Ap + (size_t)((n0 + wn * 64) >> 4) * 4096 + (size_t)lane * 8;
#pragma unroll
    for (int ni = 0; ni < 4; ++ni)
#pragma unroll
      for (int ks = 0; ks < 8; ++ks) {
        a[ni][ks] = *(const f16x8*)(ab + (size_t)(ni * 8 + ks) * 512);
        pin_frag(a[ni][ks]);
      }
  }

  float s1[4], s2[4], s3[4];
  int i1[4], i2[4];
#pragma unroll
  for (int ni = 0; ni < 4; ++ni) {
    s1[ni] = 3.4e38f;
    s2[ni] = 3.4e38f;
    s3[ni] = 3.4e38f;
    i1[ni] = 0;
    i2[ni] = 0;
  }

  const _Float16* bbase = Bp + (size_t)wc * 4096 + (size_t)lane * 8;
  const int crow = wc * 16 + ((lane >> 4) << 2);  // this lane's D-frag row base
  const f32x4 z4 = (f32x4)0.f;

  f16x8 b[8];
#pragma unroll
  for (int ks = 0; ks < 8; ++ks)
    b[ks] = *(const f16x8*)(bbase + (size_t)ks * 512);

  for (int t = 0; t < 64; ++t) {
    const float4 e4 = *(const float4*)(esq + t * 64 + crow);
    f32x4 acc0, acc1, acc2, acc3;
    __builtin_amdgcn_s_setprio(1);
#pragma unroll
    for (int ks = 0; ks < 8; ++ks) {
      acc0 = __builtin_amdgcn_mfma_f32_16x16x32_f16(b[ks], a[0][ks],
                                                    ks ? acc0 : z4, 0, 0, 0);
      acc1 = __builtin_amdgcn_mfma_f32_16x16x32_f16(b[ks], a[1][ks],
                                                    ks ? acc1 : z4, 0, 0, 0);
      acc2 = __builtin_amdgcn_mfma_f32_16x16x32_f16(b[ks], a[2][ks],
                                                    ks ? acc2 : z4, 0, 0, 0);
      acc3 = __builtin_amdgcn_mfma_f32_16x16x32_f16(b[ks], a[3][ks],
                                                    ks ? acc3 : z4, 0, 0, 0);
      // reload for step t+1 (t=63 reads the Bp pad; values unused)
      b[ks] = *(const f16x8*)(bbase + (size_t)(t + 1) * 16384 + ks * 512);
    }
    __builtin_amdgcn_s_setprio(0);
    const int cb0 = t * 64 + crow;
    const float ev[4] = {e4.x, e4.y, e4.z, e4.w};
    f32x4 accv[4] = {acc0, acc1, acc2, acc3};
#pragma unroll
    for (int r = 0; r < 4; ++r) {
      const int code = cb0 + r;
#pragma unroll
      for (int ni = 0; ni < 4; ++ni) {
        const float s = fmaf(accv[ni][r], -0.0078125f, ev[r]);
        // branchless top-3 values / top-2 indices (strict <: ties keep
        // lower code since codes ascend within a chain)
        const bool c1 = s < s1[ni];
        const bool c2 = s < s2[ni];
        const float t2v = fmaxf(s, s2[ni]);
        const float t1v = fmaxf(s, s1[ni]);
        s3[ni] = fminf(s3[ni], t2v);
        i2[ni] = c1 ? i1[ni] : (c2 ? code : i2[ni]);
        s2[ni] = fminf(s2[ni], t1v);
        i1[ni] = c1 ? code : i1[ni];
        s1[ni] = fminf(s1[ni], s);
      }
    }
  }

  // cross-quad merge via packed keys (monotone in (score, idx))
#pragma unroll
  for (int ni = 0; ni < 4; ++ni) {
    unsigned long long K0 = pack_key(s1[ni], i1[ni]);
    unsigned long long K1 = pack_key(s2[ni], i2[ni]);
    unsigned long long K2 = pack_key(s3[ni], 0xFFF);  // value-only slot
#pragma unroll
    for (int m = 16; m <= 32; m <<= 1) {
      const unsigned long long o0 = __shfl_xor(K0, m, 64);
      const unsigned long long o1 = __shfl_xor(K1, m, 64);
      const unsigned long long o2 = __shfl_xor(K2, m, 64);
      ins3(K0, K1, K2, o0);
      ins3(K0, K1, K2, o1);
      ins3(K0, K1, K2, o2);
    }
    if (lane < 16) {
      const int nl = wn * 64 + ni * 16 + lane;
      mb[nl][wc][0] = K0;
      mb[nl][wc][1] = K1;
      mb[nl][wc][2] = K2;
    }
  }
  __syncthreads();
  // finalize: top-3 over the 4 wc lists; write idx, flag, candidates
  if (tid < 128) {
    unsigned long long K0 = mb[tid][0][0];
    unsigned long long K1 = mb[tid][0][1];
    unsigned long long K2 = mb[tid][0][2];
#pragma unroll
    for (int s = 1; s < 4; ++s) {
      ins3(K0, K1, K2, mb[tid][s][0]);
      ins3(K0, K1, K2, mb[tid][s][1]);
      ins3(K0, K1, K2, mb[tid][s][2]);
    }
    const int n = n0 + tid;
    idx[n] = (int)(K0 & 0xFFFULL);
    const float sc0 = key_score(K0);
    const bool flag = key_score(K1) - sc0 < WINDOW;
    rfin[n] = flag ? ~0ull : 0ull;
    if (flag) {
      if (cand4 && (key_score(K2) - sc0 >= WINDOW_C)) {
        cand4[n] = (K0 & 0xFFFULL) | ((K1 & 0xFFFULL) << 16);
        const unsigned pos = atomicAdd(count, 1u);
        if (pos < N_VEC) list[pos] = n;
      } else {
        const unsigned p2 = atomicAdd(count2, 1u);
        if (p2 < N_VEC) listB[p2] = n;
      }
    }
  }
}

// ---- rescanB: exact f64 on the 2 certified candidates (frozen chain) -------
// 4 threads per position; j=2,3 duplicate j=0,1 (atomicMin idempotent).
// Chain per (n,k) identical to full rescan: sequential c=0..255 f64 fma in
// c,c+1,c+2,c+3 order; d = fl(fl(zsq - fl(2*(float)dot)) + esq[k]).
__global__ __launch_bounds__(256) void rescanB_kernel(
    const float* __restrict__ zT, const float* __restrict__ cb,
    const float* __restrict__ esq, const float* __restrict__ zsq,
    const int* __restrict__ list, const unsigned int* __restrict__ count,
    const unsigned long long* __restrict__ cand4,
    unsigned long long* __restrict__ rfin) {
  if (!cand4) return;
  unsigned int cN = *count;
  if (cN > N_VEC) cN = N_VEC;
  const int tid = threadIdx.x;
  const int j = tid & 3;
  for (unsigned i = blockIdx.x * 64 + (tid >> 2); i < cN; i += gridDim.x * 64) {
    const int n = list[i];
    const int k = (int)((cand4[n] >> (16 * (j & 1))) & 0xFFFULL);
    const float* zr = zT + (size_t)n * D;
    const float* row = cb + (size_t)k * D;
    double a = 0.;
    for (int c = 0; c < D; c += 4) {
      const float4 zf = *(const float4*)(zr + c);
      const float4 r4 = *(const float4*)(row + c);
      a = fma((double)zf.x, (double)r4.x, a);
      a = fma((double)zf.y, (double)r4.y, a);
      a = fma((double)zf.z, (double)r4.z, a);
      a = fma((double)zf.w, (double)r4.w, a);
    }
    const float d =
        __fadd_rn(__fsub_rn(zsq[n], __fmul_rn(2.0f, (float)a)), esq[k]);
    unsigned long long best = pack_key(d, k);
    best = min(best, __shfl_xor(best, 1, 64));
    best = min(best, __shfl_xor(best, 2, 64));
    if (j == 0) atomicMin(rfin + n, best);
  }
}

// ---- rescan (full-scan fallback for uncertified positions; frozen) ---------
__global__ __launch_bounds__(256) void rescan_kernel(
    const float* __restrict__ z, const float* __restrict__ zT,
    const float* __restrict__ cb, const float* __restrict__ esq,
    const float* __restrict__ zsq, const int* __restrict__ list,
    const unsigned int* __restrict__ count,
    unsigned long long* __restrict__ rfin) {
  __shared__ double zrow[RG][D];
  __shared__ int nloc[RG];
  __shared__ float zsv[RG];
  const int tid = threadIdx.x;
  const int lane = tid & 63;
  unsigned int cnt = *count;
  if (cnt > N_VEC) cnt = N_VEC;
  const unsigned G = (cnt + RG - 1) / RG;
  const unsigned nitems = G * (K_CODES / RSLICE);
  for (unsigned item = blockIdx.x; item < nitems; item += gridDim.x) {
    const unsigned g = item >> 4;
    const int s = item & 15;
    __syncthreads();
    if (tid < RG) {
      const unsigned r = g * RG + tid;
      const int n = (r < cnt) ? list[r] : list[cnt - 1];  // dup-pad: idempotent
      nloc[tid] = n;
      zsv[tid] = zsq[n];
    }
    __syncthreads();
    if (zT) {
      for (int i = tid; i < RG * D; i += 256) {
        const int p = i >> 8, c = i & 255;
        zrow[p][c] = (double)zT[(size_t)nloc[p] * D + c];
      }
    } else {
      for (int i = tid; i < RG * D; i += 256) {
        const int p = i >> 8, c = i & 255;
        const int n = nloc[p];
        const int b = n >> 10, hw = n & 1023;
        zrow[p][c] = (double)z[((size_t)b << 18) + ((size_t)c << 10) + hw];
      }
    }
    __syncthreads();
    const int k = s * RSLICE + tid;
    const float* row = cb + (size_t)k * D;
    double acc[RG];
#pragma unroll
    for (int p = 0; p < RG; ++p) acc[p] = 0.;
    for (int c = 0; c < D; c += 4) {
      const float4 r4 = *(const float4*)(row + c);
      const double rx = (double)r4.x, ry = (double)r4.y;
      const double rz = (double)r4.z, rw = (double)r4.w;
#pragma unroll
      for (int p = 0; p < RG; ++p) {
        const double2 za = *(const double2*)&zrow[p][c];
        const double2 zb = *(const double2*)&zrow[p][c + 2];
        double a = acc[p];
        a = fma(za.x, rx, a);
        a = fma(za.y, ry, a);
        a = fma(zb.x, rz, a);
        a = fma(zb.y, rw, a);
        acc[p] = a;
      }
    }
    const float ek = esq[k];
    unsigned long long best[RG];
#pragma unroll
    for (int p = 0; p < RG; ++p) {
      const float dotf = (float)acc[p];
      const float d = __fadd_rn(__fsub_rn(zsv[p], __fmul_rn(2.0f, dotf)), ek);
      best[p] = pack_key(d, k);
    }
#pragma unroll
    for (int p = 0; p < RG; ++p) {
#pragma unroll
      for (int off = 32; off > 0; off >>= 1)
        best[p] = min(best[p], __shfl_down(best[p], off, 64));
    }
    if (lane == 0) {
#pragma unroll
      for (int p = 0; p < RG; ++p) atomicMin(rfin + nloc[p], best[p]);
    }
  }
}

// ---- gather z_q + indices + loss (cb reads float4-ized) --------------------
__global__ __launch_bounds__(256) void gather_kernel(
    const float* __restrict__ z, const float* __restrict__ cb,
    const int* __restrict__ idxarr, const unsigned long long* __restrict__ rfin,
    float* __restrict__ out, float* __restrict__ loss_acc,
    unsigned int* __restrict__ done) {
  const int tid = threadIdx.x;
  const int n0 = blockIdx.x * 64;
  const int hwl = tid & 63;
  const int cq = tid >> 6;  // c block [cq*64, cq*64+64)
  const int n = n0 + hwl;
  const int b = n >> 10;
  const int hw = n & 1023;
  const unsigned long long rf = rfin[n];
  const int idx = rf ? (int)(rf & 0xFFFULL) : idxarr[n];
  if (tid < 64) out[(size_t)N_ELEM + 1 + n] = (float)idx;
  const float* crow = cb + (size_t)idx * D;
  const size_t obase = ((size_t)b << 18) + hw;
  float part = 0.f;
#pragma unroll
  for (int j = 0; j < 16; ++j) {
    const int c = cq * 64 + j * 4;
    const float4 v4 = *(const float4*)(crow + c);
    const size_t o = obase + ((size_t)c << 10);
    const float d0 = v4.x - z[o];
    const float d1 = v4.y - z[o + 1024];
    const float d2 = v4.z - z[o + 2048];
    const float d3 = v4.w - z[o + 3072];
    out[o] = v4.x;
    out[o + 1024] = v4.y;
    out[o + 2048] = v4.z;
    out[o + 3072] = v4.w;
    part = fmaf(d0, d0, part);
    part = fmaf(d1, d1, part);
    part = fmaf(d2, d2, part);
    part = fmaf(d3, d3, part);
  }
#pragma unroll
  for (int off = 32; off > 0; off >>= 1) part += __shfl_down(part, off, 64);
  __shared__ float red[4];
  if ((tid & 63) == 0) red[tid >> 6] = part;
  __syncthreads();
  if (tid == 0) {
    atomicAdd(loss_acc, red[0] + red[1] + red[2] + red[3]);
    __threadfence();
    const unsigned old = atomicAdd(done, 1u);
    if (old == gridDim.x - 1) {
      const float total = atomicAdd(loss_acc, 0.0f);
      out[N_ELEM] = 1.25f * total * (1.0f / (float)N_ELEM);
    }
  }
}

extern "C" void kernel_launch(void* const* d_in, const int* in_sizes, int n_in,
                              void* d_out, int out_size, void* d_ws,
                              size_t ws_size, hipStream_t stream) {
  const float* z = (const float*)d_in[0];
  const float* cb = (const float*)d_in[1];
  float* out = (float*)d_out;
  char* ws = (char*)d_ws;
  float* loss_acc = (float*)(ws + WS_LOSS);
  unsigned int* count = (unsigned int*)(ws + WS_COUNT);
  unsigned int* done = (unsigned int*)(ws + WS_DONE);
  unsigned int* count2 = (unsigned int*)(ws + WS_COUNT2);
  int* idx = (int*)(ws + WS_IDX);
  int* list = (int*)(ws + WS_LIST);
  float* esq = (float*)(ws + WS_ESQ);
  float* zsq = (float*)(ws + WS_ZSQ);
  _Float16* Ap = (_Float16*)(ws + WS_APACK);
  _Float16* Bp = (_Float16*)(ws + WS_BPACK);
  unsigned long long* rfin = (unsigned long long*)(ws + WS_RFIN);
  float* zT = (ws_size >= WS_NEED_ZT) ? (float*)(ws + WS_ZT) : nullptr;
  const bool canduse = (ws_size >= WS_NEED_CAND) && (zT != nullptr);
  unsigned long long* cand4 =
      canduse ? (unsigned long long*)(ws + WS_CAND4) : nullptr;
  int* listB = canduse ? (int*)(ws + WS_LISTB) : list;

  hipMemsetAsync(ws, 0, 256, stream);
  prep_kernel<<<PREP_BLOCKS, 256, 0, stream>>>(z, cb, esq, zsq, Ap, Bp, zT);
  dist2_kernel<<<N_VEC / 128, 512, 0, stream>>>(Ap, Bp, esq, idx, list, count,
                                                rfin, cand4, listB, count2);
  rescanB_kernel<<<512, 256, 0, stream>>>(zT, cb, esq, zsq, list, count, cand4,
                                          rfin);
  rescan_kernel<<<2048, 256, 0, stream>>>(z, zT, cb, esq, zsq, listB, count2,
                                          rfin);
  gather_kernel<<<N_VEC / 64, 256, 0, stream>>>(z, cb, idx, rfin, out,
                                                loss_acc, done);
}